// Round 1
// baseline (3464.792 us; speedup 1.0000x reference)
//
#include <hip/hip_runtime.h>

typedef __attribute__((ext_vector_type(8))) short bf16x8;
typedef __attribute__((ext_vector_type(4))) float f32x4;
typedef __attribute__((ext_vector_type(2))) float f32x2;

constexpr int   HD      = 128;
constexpr float T_NEAR  = 0.2f;
constexpr float T_FAR   = 2.0f;
constexpr float ALPHA_C = 100.0f;
constexpr int   MARCH_N = 32;
constexpr float HIT_EPS = 0.005f;
constexpr int   TP_N    = 32;
constexpr float STEP    = 0.0634765625f;  // (2.0 + 0.5*(2/32))/32, exact

// ---------- bf16 helpers ----------
__device__ __forceinline__ unsigned short f2bf(float x) {
  unsigned u = __float_as_uint(x);
  unsigned r = 0x7fffu + ((u >> 16) & 1u);
  return (unsigned short)((u + r) >> 16);
}

union U8 { bf16x8 v; uint4 u4; unsigned short us[8]; };

// packed fp32 fma: d = a*b + c (VOP3P, 1 instr for 2 floats)
__device__ __forceinline__ f32x2 pk_fma(f32x2 a, f32x2 b, f32x2 c) {
  f32x2 d;
  asm("v_pk_fma_f32 %0, %1, %2, %3" : "=v"(d) : "v"(a), "v"(b), "v"(c));
  return d;
}

// {h.x,h.y} -> packed bf16 pair (round-half-up) with relu applied in bf16-bit
// domain (max_i16 vs 0 zeroes any negative bf16; sign-exact).
__device__ __forceinline__ unsigned pack_relu_pair(f32x2 h) {
  unsigned u0 = __float_as_uint(h.x) + 0x8000u;
  unsigned u1 = __float_as_uint(h.y) + 0x8000u;
  unsigned w, r;
  asm("v_perm_b32 %0, %1, %2, %3" : "=v"(w) : "v"(u1), "v"(u0), "s"(0x07060302u));
  asm("v_pk_max_i16 %0, %1, %2" : "=v"(r) : "v"(w), "v"(0u));
  return r;
}

// ---------- setup kernel: pack W2^T into per-lane MFMA A-fragments ----------
__global__ void pack_w2(const float* __restrict__ W2,
                        unsigned short* __restrict__ hi,
                        unsigned short* __restrict__ lo) {
  int idx = blockIdx.x * 256 + threadIdx.x;     // 0..16383
  int j = idx & 7, l = (idx >> 3) & 63, t = (idx >> 9) & 7, s = idx >> 12;
  int m = 16 * t + (l & 15);
  int k = 32 * s + (l >> 4) * 8 + j;
  float w = W2[k * HD + m];
  unsigned short h = f2bf(w);
  float hf = __uint_as_float(((unsigned)h) << 16);
  hi[idx] = h;
  lo[idx] = f2bf(w - hf);
}

// ---------- shared epilogue: relu + W3 dot + cross-quad reduce (bit-identical) ----------
__device__ __forceinline__ float sdf_reduce(const f32x4 (&acc)[8],
                                            const f32x2 (&w3p)[16], float b3v) {
  f32x2 e0; e0.x = 0.f; e0.y = 0.f;
  f32x2 e1 = e0, e2 = e0, e3 = e0;
  #pragma unroll
  for (int u = 0; u < 8; ++u) {
    f32x4 y = acc[u];
    f32x2 lo; lo.x = fmaxf(y.x, 0.f); lo.y = fmaxf(y.y, 0.f);
    f32x2 hi; hi.x = fmaxf(y.z, 0.f); hi.y = fmaxf(y.w, 0.f);
    if (u & 1) { e2 = pk_fma(lo, w3p[2*u], e2); e3 = pk_fma(hi, w3p[2*u+1], e3); }
    else       { e0 = pk_fma(lo, w3p[2*u], e0); e1 = pk_fma(hi, w3p[2*u+1], e1); }
  }
  float d = (e0.x + e0.y) + (e1.x + e1.y) + ((e2.x + e2.y) + (e3.x + e3.y));
  d += __shfl_xor(d, 16);
  d += __shfl_xor(d, 32);
  return d + b3v;
}

// ---------- dual fast eval: two independent ray-groups, interleaved MFMA chains ----------
// Group B's MFMAs fill group A's VALU/latency gaps (1 wave/SIMD, in-order issue).
__device__ __forceinline__ void sdf_fast_dual(float tA, float tB,
    const bf16x8 (&w2f)[4][8],
    const f32x2 (&apA)[16], const f32x2 (&cpA)[16],
    const f32x2 (&apB)[16], const f32x2 (&cpB)[16],
    const f32x4 (&b2f)[8], const f32x2 (&w3p)[16], float b3v,
    float& dA, float& dB)
{
  f32x2 tA2; tA2.x = tA; tA2.y = tA;
  f32x2 tB2; tB2.x = tB; tB2.y = tB;
  U8 BA[4], BB[4];
  #pragma unroll
  for (int s = 0; s < 4; ++s) {
    uint4 ua;
    ua.x = pack_relu_pair(pk_fma(cpA[4*s+0], tA2, apA[4*s+0]));
    ua.y = pack_relu_pair(pk_fma(cpA[4*s+1], tA2, apA[4*s+1]));
    ua.z = pack_relu_pair(pk_fma(cpA[4*s+2], tA2, apA[4*s+2]));
    ua.w = pack_relu_pair(pk_fma(cpA[4*s+3], tA2, apA[4*s+3]));
    BA[s].u4 = ua;
    uint4 ub;
    ub.x = pack_relu_pair(pk_fma(cpB[4*s+0], tB2, apB[4*s+0]));
    ub.y = pack_relu_pair(pk_fma(cpB[4*s+1], tB2, apB[4*s+1]));
    ub.z = pack_relu_pair(pk_fma(cpB[4*s+2], tB2, apB[4*s+2]));
    ub.w = pack_relu_pair(pk_fma(cpB[4*s+3], tB2, apB[4*s+3]));
    BB[s].u4 = ub;
  }

  f32x4 accA[8], accB[8];
  #pragma unroll
  for (int u = 0; u < 8; ++u) {   // b2 folded in as C operand
    accA[u] = __builtin_amdgcn_mfma_f32_16x16x32_bf16(w2f[0][u], BA[0].v, b2f[u], 0, 0, 0);
    accB[u] = __builtin_amdgcn_mfma_f32_16x16x32_bf16(w2f[0][u], BB[0].v, b2f[u], 0, 0, 0);
  }
  #pragma unroll
  for (int s = 1; s < 4; ++s)
    #pragma unroll
    for (int u = 0; u < 8; ++u) {
      accA[u] = __builtin_amdgcn_mfma_f32_16x16x32_bf16(w2f[s][u], BA[s].v, accA[u], 0, 0, 0);
      accB[u] = __builtin_amdgcn_mfma_f32_16x16x32_bf16(w2f[s][u], BB[s].v, accB[u], 0, 0, 0);
    }

  dA = sdf_reduce(accA, w3p, b3v);
  dB = sdf_reduce(accB, w3p, b3v);
}

// ---------- hi/lo-split precise eval (x100 tput channel), unchanged math ----------
__device__ __forceinline__ float sdf_precise(float t, int lane,
    const bf16x8 (&w2f)[4][8], const f32x2 (&ap)[16], const f32x2 (&cp)[16],
    const f32x4 (&b2f)[8], const f32x2 (&w3p)[16], float b3v,
    const unsigned short* __restrict__ wlo)
{
  U8 HH[4], HL[4];
  #pragma unroll
  for (int s = 0; s < 4; ++s) {
    #pragma unroll
    for (int p = 0; p < 4; ++p) {
      float h0 = fmaxf(fmaf(cp[4*s+p].x, t, ap[4*s+p].x), 0.f);
      float h1 = fmaxf(fmaf(cp[4*s+p].y, t, ap[4*s+p].y), 0.f);
      unsigned short hb0 = f2bf(h0), hb1 = f2bf(h1);
      float r0 = h0 - __uint_as_float(((unsigned)hb0) << 16);
      float r1 = h1 - __uint_as_float(((unsigned)hb1) << 16);
      HH[s].us[2*p]     = hb0;      HH[s].us[2*p + 1] = hb1;
      HL[s].us[2*p]     = f2bf(r0); HL[s].us[2*p + 1] = f2bf(r1);
    }
  }

  const bf16x8* wloF = (const bf16x8*)wlo;
  f32x4 acc[8];
  #pragma unroll
  for (int u = 0; u < 8; ++u)
    acc[u] = __builtin_amdgcn_mfma_f32_16x16x32_bf16(w2f[0][u], HH[0].v, b2f[u], 0, 0, 0);
  #pragma unroll
  for (int s = 0; s < 4; ++s) {
    #pragma unroll
    for (int u = 0; u < 8; ++u) {
      bf16x8 wl = wloF[(s * 8 + u) * 64 + lane];
      if (s > 0)
        acc[u] = __builtin_amdgcn_mfma_f32_16x16x32_bf16(w2f[s][u], HH[s].v, acc[u], 0, 0, 0);
      acc[u] = __builtin_amdgcn_mfma_f32_16x16x32_bf16(wl, HH[s].v, acc[u], 0, 0, 0);
      acc[u] = __builtin_amdgcn_mfma_f32_16x16x32_bf16(w2f[s][u], HL[s].v, acc[u], 0, 0, 0);
    }
  }

  return sdf_reduce(acc, w3p, b3v);
}

// ---------- main: 1 wave = 32 rays (2 independent groups of 16) ----------
__global__ __launch_bounds__(256, 1)
void render(const float* __restrict__ rays,
            const float* __restrict__ W1, const float* __restrict__ b1,
            const float* __restrict__ b2, const float* __restrict__ W3,
            const float* __restrict__ b3,
            const float* __restrict__ R1, const float* __restrict__ rb1,
            const float* __restrict__ R2, const float* __restrict__ rb2,
            const unsigned short* __restrict__ whi,
            const unsigned short* __restrict__ wlo,
            float* __restrict__ out, int nrays)
{
  const int tid  = threadIdx.x;
  const int lane = tid & 63;
  const int q    = lane >> 4;
  const int wv   = tid >> 6;
  const int rayA = blockIdx.x * 128 + wv * 32 + (lane & 15);
  const int rayB = rayA + 16;

  // W2^T hi fragments resident (shared by both groups): 128 regs
  bf16x8 w2f[4][8];
  const bf16x8* whiF = (const bf16x8*)whi;
  #pragma unroll
  for (int s = 0; s < 4; ++s)
    #pragma unroll
    for (int u = 0; u < 8; ++u)
      w2f[s][u] = whiF[(s * 8 + u) * 64 + lane];

  const float roxA = rays[rayA * 6 + 0];
  const float royA = rays[rayA * 6 + 1];
  const float rozA = rays[rayA * 6 + 2];
  const float rdxA = rays[rayA * 6 + 3];
  const float rdyA = rays[rayA * 6 + 4];
  const float rdzA = rays[rayA * 6 + 5];
  const float roxB = rays[rayB * 6 + 0];
  const float royB = rays[rayB * 6 + 1];
  const float rozB = rays[rayB * 6 + 2];
  const float rdxB = rays[rayB * 6 + 3];
  const float rdyB = rays[rayB * 6 + 4];
  const float rdzB = rays[rayB * 6 + 5];
  const float b3v = b3[0];

  // a[k] = W1^T ro + b1, c[k] = W1^T rd  (fp32, register-resident, pair-packed)
  f32x2 apA[16], cpA[16], apB[16], cpB[16];
  #pragma unroll
  for (int s = 0; s < 4; ++s)
    #pragma unroll
    for (int p = 0; p < 4; ++p) {
      int k0 = 32 * s + 8 * q + 2 * p;
      int k1 = k0 + 1;
      float x0 = W1[k0], y0 = W1[HD + k0], z0 = W1[2 * HD + k0], g0 = b1[k0];
      float x1 = W1[k1], y1 = W1[HD + k1], z1 = W1[2 * HD + k1], g1 = b1[k1];
      f32x2 a, c;
      a.x = fmaf(x0, roxA, fmaf(y0, royA, fmaf(z0, rozA, g0)));
      a.y = fmaf(x1, roxA, fmaf(y1, royA, fmaf(z1, rozA, g1)));
      c.x = fmaf(x0, rdxA, fmaf(y0, rdyA, z0 * rdzA));
      c.y = fmaf(x1, rdxA, fmaf(y1, rdyA, z1 * rdzA));
      apA[4 * s + p] = a;
      cpA[4 * s + p] = c;
      a.x = fmaf(x0, roxB, fmaf(y0, royB, fmaf(z0, rozB, g0)));
      a.y = fmaf(x1, roxB, fmaf(y1, royB, fmaf(z1, rozB, g1)));
      c.x = fmaf(x0, rdxB, fmaf(y0, rdyB, z0 * rdzB));
      c.y = fmaf(x1, rdxB, fmaf(y1, rdyB, z1 * rdzB));
      apB[4 * s + p] = a;
      cpB[4 * s + p] = c;
    }

  // b2 as MFMA C-init fragments; W3 as fp32 pairs (shared)
  f32x4 b2f[8];
  f32x2 w3p[16];
  #pragma unroll
  for (int u = 0; u < 8; ++u) {
    int n0 = 16 * u + 4 * q;
    f32x4 bb; bb.x = b2[n0]; bb.y = b2[n0 + 1]; bb.z = b2[n0 + 2]; bb.w = b2[n0 + 3];
    b2f[u] = bb;
    f32x2 wa; wa.x = W3[n0];     wa.y = W3[n0 + 1];
    f32x2 wb; wb.x = W3[n0 + 2]; wb.y = W3[n0 + 3];
    w3p[2 * u] = wa; w3p[2 * u + 1] = wb;
  }

  // ---- sphere march: both groups in lockstep (frozen-state no-ops once a
  // group is fully hit, so results are bit-identical to independent marches) ----
  float cdA = T_NEAR, cdB = T_NEAR;
  bool hitA = false, hitB = false;
  #pragma unroll 1
  for (int it = 0; it < MARCH_N; ++it) {
    float dA, dB;
    sdf_fast_dual(cdA, cdB, w2f, apA, cpA, apB, cpB, b2f, w3p, b3v, dA, dB);
    bool nhA = (dA < HIT_EPS) && (cdA >= T_NEAR) && (cdA <= T_FAR);
    hitA = hitA || nhA;
    cdA = hitA ? cdA : cdA + dA;
    bool nhB = (dB < HIT_EPS) && (cdB >= T_NEAR) && (cdB <= T_FAR);
    hitB = hitB || nhB;
    cdB = hitB ? cdB : cdB + dB;
    if ((__ballot(!hitA) | __ballot(!hitB)) == 0ull) break;
  }

  // ---- reflectance (exact fp32), R1/R2 rows shared across both groups ----
  const float ptxA = fmaf(rdxA, cdA, roxA);
  const float ptyA = fmaf(rdyA, cdA, royA);
  const float ptzA = fmaf(rdzA, cdA, rozA);
  const float ptxB = fmaf(rdxB, cdB, roxB);
  const float ptyB = fmaf(rdyB, cdB, royB);
  const float ptzB = fmaf(rdzB, cdB, rozB);
  float crA = 0.f, cgA = 0.f, cbA = 0.f;
  float crB = 0.f, cgB = 0.f, cbB = 0.f;
  {
    int jb = q * 32;
    #pragma unroll 1
    for (int jj = 0; jj < 32; ++jj) {
      int j = jb + jj;
      float r0 = R1[0 * HD + j], r1 = R1[1 * HD + j], r2 = R1[2 * HD + j];
      float r3 = R1[3 * HD + j], r4 = R1[4 * HD + j], r5 = R1[5 * HD + j];
      float rb = rb1[j];
      float hA = fmaf(r0, ptxA, fmaf(r1, ptyA, fmaf(r2, ptzA,
                 fmaf(r3, rdxA, fmaf(r4, rdyA, fmaf(r5, rdzA, rb))))));
      hA = fmaxf(hA, 0.f);
      float hB = fmaf(r0, ptxB, fmaf(r1, ptyB, fmaf(r2, ptzB,
                 fmaf(r3, rdxB, fmaf(r4, rdyB, fmaf(r5, rdzB, rb))))));
      hB = fmaxf(hB, 0.f);
      float s0 = R2[j * 3 + 0], s1 = R2[j * 3 + 1], s2 = R2[j * 3 + 2];
      crA = fmaf(hA, s0, crA); cgA = fmaf(hA, s1, cgA); cbA = fmaf(hA, s2, cbA);
      crB = fmaf(hB, s0, crB); cgB = fmaf(hB, s1, cgB); cbB = fmaf(hB, s2, cbB);
    }
    crA += __shfl_xor(crA, 16); crA += __shfl_xor(crA, 32);
    cgA += __shfl_xor(cgA, 16); cgA += __shfl_xor(cgA, 32);
    cbA += __shfl_xor(cbA, 16); cbA += __shfl_xor(cbA, 32);
    crB += __shfl_xor(crB, 16); crB += __shfl_xor(crB, 32);
    cgB += __shfl_xor(cgB, 16); cgB += __shfl_xor(cgB, 32);
    cbB += __shfl_xor(cbB, 16); cbB += __shfl_xor(cbB, 32);
    crA += rb2[0]; cgA += rb2[1]; cbA += rb2[2];
    crB += rb2[0]; cgB += rb2[1]; cbB += rb2[2];
  }

  // ---- tube scan: argmin of sdf over t = s*STEP, s = 0..32, both groups ----
  float mnA, mnB;
  sdf_fast_dual(0.f, 0.f, w2f, apA, cpA, apB, cpB, b2f, w3p, b3v, mnA, mnB);
  int idxA = 0, idxB = 0;
  float ts = 0.f;
  #pragma unroll 1
  for (int s = 1; s <= TP_N; ++s) {
    ts += STEP;                       // exact (65*s/1024, s<=32)
    float dA, dB;
    sdf_fast_dual(ts, ts, w2f, apA, cpA, apB, cpB, b2f, w3p, b3v, dA, dB);
    if (dA < mnA) { mnA = dA; idxA = s; }
    if (dB < mnB) { mnB = dB; idxB = s; }
  }

  // ---- final tput at best t, hi/lo split (sequential: keeps register peak down) ----
  const float tbA = STEP * (float)idxA;
  const float tputA = sdf_precise(tbA, lane, w2f, apA, cpA, b2f, w3p, b3v, wlo);
  const float tbB = STEP * (float)idxB;
  const float tputB = sdf_precise(tbB, lane, w2f, apB, cpB, b2f, w3p, b3v, wlo);

  if (q == 0) {
    float4 o;
    o.x = hitA ? crA : 0.f;
    o.y = hitA ? cgA : 0.f;
    o.z = hitA ? cbA : 0.f;
    o.w = -ALPHA_C * tputA;
    ((float4*)out)[rayA] = o;
  } else if (q == 1) {
    float4 o;
    o.x = hitB ? crB : 0.f;
    o.y = hitB ? cgB : 0.f;
    o.z = hitB ? cbB : 0.f;
    o.w = -ALPHA_C * tputB;
    ((float4*)out)[rayB] = o;
  }
}

extern "C" void kernel_launch(void* const* d_in, const int* in_sizes, int n_in,
                              void* d_out, int out_size, void* d_ws, size_t ws_size,
                              hipStream_t stream) {
  const float* rays = (const float*)d_in[0];
  const float* W1  = (const float*)d_in[1];
  const float* b1  = (const float*)d_in[2];
  const float* W2  = (const float*)d_in[3];
  const float* b2  = (const float*)d_in[4];
  const float* W3  = (const float*)d_in[5];
  const float* b3  = (const float*)d_in[6];
  const float* R1  = (const float*)d_in[7];
  const float* rb1 = (const float*)d_in[8];
  const float* R2  = (const float*)d_in[9];
  const float* rb2 = (const float*)d_in[10];

  unsigned short* whi = (unsigned short*)d_ws;   // 32 KB
  unsigned short* wlo = whi + 128 * 128;         // 32 KB

  const int nrays = in_sizes[0] / 6;

  hipLaunchKernelGGL(pack_w2, dim3(64), dim3(256), 0, stream, W2, whi, wlo);
  hipLaunchKernelGGL(render, dim3(nrays / 128), dim3(256), 0, stream,
                     rays, W1, b1, b2, W3, b3, R1, rb1, R2, rb2,
                     whi, wlo, (float*)d_out, nrays);
}